// Round 7
// baseline (229.876 us; speedup 1.0000x reference)
//
#include <hip/hip_runtime.h>
#include <hip/hip_fp16.h>

#define NN 100000
#define NE 1600000
#define NG 512
#define F  32

#define BSH    8                              // 256 dst-nodes per bucket
#define BNODES 256
#define NB     ((NN + BNODES - 1) / BNODES)   // 391
#define CCHUNK 2048
#define NWGC   ((NE + CCHUNK - 1) / CCHUNK)   // 782 (count)
#define PCHUNK 4096
#define NWGP   ((NE + PCHUNK - 1) / PCHUNK)   // 391 (partition)

// ---- per-WG LDS histogram of dst buckets -> global bucket totals ----
__global__ void k_count(const int* __restrict__ dst, int* __restrict__ btot) {
    __shared__ int hist[NB];
    int tid = threadIdx.x;
    for (int i = tid; i < NB; i += 256) hist[i] = 0;
    __syncthreads();
    int e0 = blockIdx.x * CCHUNK;
    int e1 = min(e0 + CCHUNK, NE);
    for (int e = e0 + tid; e < e1; e += 256) atomicAdd(&hist[dst[e] >> BSH], 1);
    __syncthreads();
    for (int i = tid; i < NB; i += 256)
        if (hist[i]) atomicAdd(&btot[i], hist[i]);
}

// ---- scan bucket totals -> bucket_start[NB+1]; init cursors. one 512-block ----
__global__ void k_bscan(const int* __restrict__ btot, int* __restrict__ bstart,
                        int* __restrict__ cursor) {
    __shared__ int lds[512];
    int tid = threadIdx.x;
    int v = (tid < NB) ? btot[tid] : 0;
    lds[tid] = v;
    __syncthreads();
    for (int o = 1; o < 512; o <<= 1) {
        int t = (tid >= o) ? lds[tid - o] : 0;
        __syncthreads();
        lds[tid] += t;
        __syncthreads();
    }
    int excl = lds[tid] - v;
    if (tid < NB) { bstart[tid] = excl; cursor[tid] = excl; }
    if (tid == 0) bstart[NB] = NE;
}

// ---- partition edges into bucket-contiguous packed (src<<8)|(dst&255). WG=512 ----
__global__ void k_partition(const int* __restrict__ src, const int* __restrict__ dst,
                            int* __restrict__ cursor, int* __restrict__ part) {
    __shared__ int hist[NB];
    __shared__ int base[NB];
    int tid = threadIdx.x;
    for (int i = tid; i < NB; i += 512) hist[i] = 0;
    __syncthreads();
    int e0 = blockIdx.x * PCHUNK;
    int e1 = min(e0 + PCHUNK, NE);
    for (int e = e0 + tid; e < e1; e += 512) atomicAdd(&hist[dst[e] >> BSH], 1);
    __syncthreads();
    for (int i = tid; i < NB; i += 512) {
        base[i] = hist[i] ? atomicAdd(&cursor[i], hist[i]) : 0;
        hist[i] = 0;
    }
    __syncthreads();
    for (int e = e0 + tid; e < e1; e += 512) {
        int d = dst[e];
        int b = d >> BSH;
        int p = base[b] + atomicAdd(&hist[b], 1);
        part[p] = (src[e] << 8) | (d & (BNODES - 1));
    }
}

// ---- fill2a: per-bucket histogram+scan -> row, dinv, xd ----
__global__ void k_fill2a(const int* __restrict__ part, const int* __restrict__ bstart,
                         const float* __restrict__ x,
                         int* __restrict__ row, float* __restrict__ dinv,
                         float4* __restrict__ xd) {
    __shared__ int cnt[BNODES];
    __shared__ int lds[BNODES];
    int b = blockIdx.x, tid = threadIdx.x;
    int node0 = b << BSH;
    int s0 = bstart[b], s1 = bstart[b + 1];
    cnt[tid] = 0;
    __syncthreads();
    for (int i = s0 + tid; i < s1; i += 256) atomicAdd(&cnt[part[i] & (BNODES - 1)], 1);
    __syncthreads();
    int c = cnt[tid];
    lds[tid] = c;
    __syncthreads();
    for (int o = 1; o < 256; o <<= 1) {
        int t = (tid >= o) ? lds[tid - o] : 0;
        __syncthreads();
        lds[tid] += t;
        __syncthreads();
    }
    int excl = lds[tid] - c;
    int n = node0 + tid;
    if (n < NN) {
        row[n] = s0 + excl;
        float d = rsqrtf((float)c + 1.0f);
        dinv[n] = d;
        xd[n] = make_float4(d * x[n * 3 + 0], d * x[n * 3 + 1], d * x[n * 3 + 2], d);
    }
    if (b == NB - 1 && tid == 0) row[NN] = NE;
}

// ---- fill2b: csr scatter (L2-local) + fused layer-1 3-vec aggregation ----
__global__ void k_fill2b(const int* __restrict__ part, const int* __restrict__ bstart,
                         const int* __restrict__ row, const float4* __restrict__ xd,
                         int* __restrict__ csr, float4* __restrict__ combine) {
    __shared__ int off[BNODES];
    __shared__ float accx[BNODES];
    __shared__ float accy[BNODES];
    __shared__ float accz[BNODES];
    int b = blockIdx.x, tid = threadIdx.x;
    int node0 = b << BSH;
    int s0 = bstart[b], s1 = bstart[b + 1];
    int n = node0 + tid;
    off[tid]  = (n < NN) ? (row[n] - s0) : 0;
    accx[tid] = 0.0f; accy[tid] = 0.0f; accz[tid] = 0.0f;
    __syncthreads();
    for (int i = s0 + tid; i < s1; i += 256) {
        int p = part[i];
        int ln = p & (BNODES - 1);
        int s = p >> 8;
        int pos = s0 + atomicAdd(&off[ln], 1);
        csr[pos] = s;
        float4 v = xd[s];
        atomicAdd(&accx[ln], v.x);
        atomicAdd(&accy[ln], v.y);
        atomicAdd(&accz[ln], v.z);
    }
    __syncthreads();
    if (n < NN) {
        float4 sf = xd[n];
        float dn = sf.w;
        combine[n] = make_float4(dn * (accx[tid] + sf.x),
                                 dn * (accy[tid] + sf.y),
                                 dn * (accz[tid] + sf.z), 0.0f);
    }
}

// h1 = relu(combine @ W1 + b1), packed half2. one thread per feature-pair.
__global__ void k_proj1(const float4* __restrict__ combine, const float* __restrict__ W1,
                        const float* __restrict__ b1, __half2* __restrict__ h1) {
    int idx = blockIdx.x * blockDim.x + threadIdx.x;
    if (idx >= NN * 16) return;
    int n = idx >> 4, j = idx & 15;
    float4 c = combine[n];
    int f0 = 2 * j, f1 = 2 * j + 1;
    float v0 = c.x * W1[0 * F + f0] + c.y * W1[1 * F + f0] + c.z * W1[2 * F + f0] + b1[f0];
    float v1 = c.x * W1[0 * F + f1] + c.y * W1[1 * F + f1] + c.z * W1[2 * F + f1] + b1[f1];
    h1[idx] = __floats2half2_rn(fmaxf(v0, 0.0f), fmaxf(v1, 0.0f));
}

// ================= layer 2 =================
// t[n] = dn*sum_e dinv[s]*h1[s] + dn^2*h1[n]   (W2 applied later — linearity)
__global__ void k_gather2h(const int* __restrict__ row, const int* __restrict__ csr,
                           const __half2* __restrict__ h1, const float* __restrict__ dinv,
                           __half2* __restrict__ t16) {
    int tid = threadIdx.x;
    int n = blockIdx.x * 16 + (tid >> 4);
    if (n >= NN) return;
    int j = tid & 15;
    int beg = row[n], end = row[n + 1];
    float ax = 0.0f, ay = 0.0f;
    int e = beg;
    for (; e + 3 < end; e += 4) {
        int s0 = csr[e], s1 = csr[e + 1], s2 = csr[e + 2], s3 = csr[e + 3];
        float d0 = dinv[s0], d1 = dinv[s1], d2 = dinv[s2], d3 = dinv[s3];
        float2 v0 = __half22float2(h1[s0 * 16 + j]);
        float2 v1 = __half22float2(h1[s1 * 16 + j]);
        float2 v2 = __half22float2(h1[s2 * 16 + j]);
        float2 v3 = __half22float2(h1[s3 * 16 + j]);
        ax += d0 * v0.x + d1 * v1.x + d2 * v2.x + d3 * v3.x;
        ay += d0 * v0.y + d1 * v1.y + d2 * v2.y + d3 * v3.y;
    }
    for (; e < end; ++e) {
        int s = csr[e];
        float d = dinv[s];
        float2 v = __half22float2(h1[s * 16 + j]);
        ax += d * v.x;
        ay += d * v.y;
    }
    float dn = dinv[n];
    float2 sf = __half22float2(h1[n * 16 + j]);
    float tx = dn * ax + dn * dn * sf.x;
    float ty = dn * ay + dn * dn * sf.y;
    t16[n * 16 + j] = __floats2half2_rn(tx, ty);
}

// ================= fused proj2 + relu + pool + head =================
__global__ void k_proj2_pool_head(const __half2* __restrict__ t16,
                                  const int* __restrict__ batch,
                                  const float* __restrict__ W2, const float* __restrict__ b2,
                                  const float* __restrict__ Wl, const float* __restrict__ bl,
                                  float* __restrict__ out) {
    __shared__ float W2s[F * F];
    __shared__ float ts[8][F];
    __shared__ float red[8][F];
    __shared__ float mean[F];
    __shared__ int range[2];
    int g = blockIdx.x, tid = threadIdx.x;
    for (int i = tid; i < F * F; i += 256) W2s[i] = W2[i];
    if (tid < 2) {
        int key = g + tid, lo = 0, hi = NN;
        while (lo < hi) {
            int mid = (lo + hi) >> 1;
            if (batch[mid] < key) lo = mid + 1; else hi = mid;
        }
        range[tid] = lo;
    }
    __syncthreads();
    int s = range[0], e = range[1];
    int grp = tid >> 5, f = tid & 31;
    float b2f = b2[f];
    float psum = 0.0f;
    for (int n0 = s; n0 < e; n0 += 8) {
        __syncthreads();
        if (tid < 128) {
            int nl = tid >> 4, j = tid & 15;
            int n = n0 + nl;
            if (n < e) {
                float2 v = __half22float2(t16[n * 16 + j]);
                ts[nl][2 * j]     = v.x;
                ts[nl][2 * j + 1] = v.y;
            }
        }
        __syncthreads();
        int n = n0 + grp;
        if (n < e) {
            float acc = b2f;
#pragma unroll
            for (int k = 0; k < F; k++) acc += ts[grp][k] * W2s[k * F + f];
            psum += fmaxf(acc, 0.0f);
        }
    }
    red[grp][f] = psum;
    __syncthreads();
    if (grp == 0) {
        float t = red[0][f] + red[1][f] + red[2][f] + red[3][f]
                + red[4][f] + red[5][f] + red[6][f] + red[7][f];
        mean[f] = t / fmaxf((float)(e - s), 1.0f);
    }
    __syncthreads();
    if (tid < 2) {
        float a = 0.0f;
#pragma unroll
        for (int k = 0; k < F; k++) a += mean[k] * Wl[k * 2 + tid];
        out[g * 2 + tid] = a + bl[tid];
    }
}

extern "C" void kernel_launch(void* const* d_in, const int* in_sizes, int n_in,
                              void* d_out, int out_size, void* d_ws, size_t ws_size,
                              hipStream_t stream) {
    const float* x     = (const float*)d_in[0];
    const int*   eidx  = (const int*)d_in[1];   // int32 per harness contract
    const int*   batch = (const int*)d_in[2];
    const float* W1    = (const float*)d_in[3];
    const float* b1    = (const float*)d_in[4];
    const float* W2    = (const float*)d_in[5];
    const float* b2    = (const float*)d_in[6];
    const float* Wl    = (const float*)d_in[7];
    const float* bl    = (const float*)d_in[8];
    float*       out   = (float*)d_out;

    const int* src = eidx;
    const int* dst = eidx + NE;

    // ---- workspace layout, 128B-aligned chunks ----
    char* base = (char*)d_ws;
    size_t off = 0;
    auto alloc = [&](size_t bytes) {
        void* p = base + off;
        off = (off + bytes + 127) & ~(size_t)127;
        return p;
    };
    int*     btot    = (int*)alloc(NB * sizeof(int));
    int*     bstart  = (int*)alloc((NB + 1) * sizeof(int));
    int*     cursor  = (int*)alloc(NB * sizeof(int));
    int*     row     = (int*)alloc((NN + 1) * sizeof(int));
    int*     csr     = (int*)alloc(NE * sizeof(int));
    int*     part    = (int*)alloc((size_t)NE * sizeof(int));   // packed (src<<8)|local_dst
    float*   dinv    = (float*)alloc(NN * sizeof(float));
    float4*  xd      = (float4*)alloc(NN * sizeof(float4));
    float4*  combine = (float4*)alloc(NN * sizeof(float4));
    __half2* h1      = (__half2*)alloc((size_t)NN * 16 * sizeof(__half2));
    __half2* t16     = (__half2*)alloc((size_t)NN * 16 * sizeof(__half2));

    const int B = 256;
    const int gNH  = (NN * 16 + B - 1) / B;       // 6250
    const int gG16 = (NN + 15) / 16;              // 6250

    // ---- CSR build: bucketed counting sort (packed 4B records) ----
    hipMemsetAsync(btot, 0, NB * sizeof(int), stream);
    k_count    <<<NWGC, B,   0, stream>>>(dst, btot);
    k_bscan    <<<1,    512, 0, stream>>>(btot, bstart, cursor);
    k_partition<<<NWGP, 512, 0, stream>>>(src, dst, cursor, part);
    k_fill2a   <<<NB,   B,   0, stream>>>(part, bstart, x, row, dinv, xd);
    k_fill2b   <<<NB,   B,   0, stream>>>(part, bstart, row, xd, csr, combine); // + fused layer-1 agg

    // ---- layer 1 projection (h1 in fp16) ----
    k_proj1<<<gNH, B, 0, stream>>>(combine, W1, b1, h1);

    // ---- layer 2: gather h1 (fp16 payload), W2 deferred ----
    k_gather2h<<<gG16, B, 0, stream>>>(row, csr, h1, dinv, t16);

    // ---- fused proj2 + relu + pool + head ----
    k_proj2_pool_head<<<NG, B, 0, stream>>>(t16, batch, W2, b2, Wl, bl, out);
}

// Round 8
// 212.152 us; speedup vs baseline: 1.0835x; 1.0835x over previous
//
#include <hip/hip_runtime.h>
#include <hip/hip_fp16.h>

#define NN 100000
#define NE 1600000
#define NG 512
#define F  32

#define BSH    8                              // 256 dst-nodes per bucket
#define BNODES 256
#define NB     ((NN + BNODES - 1) / BNODES)   // 391
#define CCHUNK 2048
#define NWGC   ((NE + CCHUNK - 1) / CCHUNK)   // 782 (count)
#define PCHUNK 4096
#define NWGP   ((NE + PCHUNK - 1) / PCHUNK)   // 391 (partition)

// ---- per-WG LDS histogram of dst buckets -> global bucket totals ----
__global__ void k_count(const int* __restrict__ dst, int* __restrict__ btot) {
    __shared__ int hist[NB];
    int tid = threadIdx.x;
    for (int i = tid; i < NB; i += 256) hist[i] = 0;
    __syncthreads();
    int e0 = blockIdx.x * CCHUNK;
    int e1 = min(e0 + CCHUNK, NE);
    for (int e = e0 + tid; e < e1; e += 256) atomicAdd(&hist[dst[e] >> BSH], 1);
    __syncthreads();
    for (int i = tid; i < NB; i += 256)
        if (hist[i]) atomicAdd(&btot[i], hist[i]);
}

// ---- scan bucket totals -> bucket_start[NB+1]; init cursors. one 512-block ----
__global__ void k_bscan(const int* __restrict__ btot, int* __restrict__ bstart,
                        int* __restrict__ cursor) {
    __shared__ int lds[512];
    int tid = threadIdx.x;
    int v = (tid < NB) ? btot[tid] : 0;
    lds[tid] = v;
    __syncthreads();
    for (int o = 1; o < 512; o <<= 1) {
        int t = (tid >= o) ? lds[tid - o] : 0;
        __syncthreads();
        lds[tid] += t;
        __syncthreads();
    }
    int excl = lds[tid] - v;
    if (tid < NB) { bstart[tid] = excl; cursor[tid] = excl; }
    if (tid == 0) bstart[NB] = NE;
}

// ---- partition edges into bucket-contiguous packed (src<<8)|(dst&255). WG=512 ----
__global__ void k_partition(const int* __restrict__ src, const int* __restrict__ dst,
                            int* __restrict__ cursor, int* __restrict__ part) {
    __shared__ int hist[NB];
    __shared__ int base[NB];
    int tid = threadIdx.x;
    for (int i = tid; i < NB; i += 512) hist[i] = 0;
    __syncthreads();
    int e0 = blockIdx.x * PCHUNK;
    int e1 = min(e0 + PCHUNK, NE);
    for (int e = e0 + tid; e < e1; e += 512) atomicAdd(&hist[dst[e] >> BSH], 1);
    __syncthreads();
    for (int i = tid; i < NB; i += 512) {
        base[i] = hist[i] ? atomicAdd(&cursor[i], hist[i]) : 0;
        hist[i] = 0;
    }
    __syncthreads();
    for (int e = e0 + tid; e < e1; e += 512) {
        int d = dst[e];
        int b = d >> BSH;
        int p = base[b] + atomicAdd(&hist[b], 1);
        part[p] = (src[e] << 8) | (d & (BNODES - 1));
    }
}

// ---- fill2: per-bucket histogram+scan -> row/dinv/xd; L2-local csr scatter ----
// single read of packed part (R6 structure, 4B records)
__global__ void k_fill2(const int* __restrict__ part, const int* __restrict__ bstart,
                        const float* __restrict__ x,
                        int* __restrict__ row, float* __restrict__ dinv,
                        float4* __restrict__ xd, int* __restrict__ csr) {
    __shared__ int cnt[BNODES];
    __shared__ int off[BNODES];
    __shared__ int lds[BNODES];
    int b = blockIdx.x, tid = threadIdx.x;
    int node0 = b << BSH;
    int s0 = bstart[b], s1 = bstart[b + 1];
    cnt[tid] = 0;
    __syncthreads();
    for (int i = s0 + tid; i < s1; i += 256) atomicAdd(&cnt[part[i] & (BNODES - 1)], 1);
    __syncthreads();
    int c = cnt[tid];
    lds[tid] = c;
    __syncthreads();
    for (int o = 1; o < 256; o <<= 1) {
        int t = (tid >= o) ? lds[tid - o] : 0;
        __syncthreads();
        lds[tid] += t;
        __syncthreads();
    }
    int excl = lds[tid] - c;
    off[tid] = excl;
    int n = node0 + tid;
    if (n < NN) {
        row[n] = s0 + excl;
        float d = rsqrtf((float)c + 1.0f);
        dinv[n] = d;
        xd[n] = make_float4(d * x[n * 3 + 0], d * x[n * 3 + 1], d * x[n * 3 + 2], d);
    }
    if (b == NB - 1 && tid == 0) row[NN] = NE;
    __syncthreads();
    for (int i = s0 + tid; i < s1; i += 256) {
        int p = part[i];
        int pos = s0 + atomicAdd(&off[p & (BNODES - 1)], 1);
        csr[pos] = p >> 8;
    }
}

// ================= layer 1: fused aggregate + project =================
// per node: c = dinv[n]*(sum_e xd[src].xyz + xd[n].xyz); h1[n] = relu(c@W1+b1) fp16
__global__ void k_agg1p(const int* __restrict__ row, const int* __restrict__ csr,
                        const float4* __restrict__ xd,
                        const float* __restrict__ W1, const float* __restrict__ b1,
                        __half2* __restrict__ h1) {
    __shared__ float W1s[3 * F];
    __shared__ float b1s[F];
    int tid = threadIdx.x;
    if (tid < 3 * F) W1s[tid] = W1[tid];
    if (tid < F) b1s[tid] = b1[tid];
    __syncthreads();
    int n = blockIdx.x * blockDim.x + tid;
    if (n >= NN) return;
    int beg = row[n], end = row[n + 1];
    float ax = 0.0f, ay = 0.0f, az = 0.0f;
    int e = beg;
    for (; e + 3 < end; e += 4) {
        int s0 = csr[e], s1 = csr[e + 1], s2 = csr[e + 2], s3 = csr[e + 3];
        float4 v0 = xd[s0], v1 = xd[s1], v2 = xd[s2], v3 = xd[s3];
        ax += (v0.x + v1.x) + (v2.x + v3.x);
        ay += (v0.y + v1.y) + (v2.y + v3.y);
        az += (v0.z + v1.z) + (v2.z + v3.z);
    }
    for (; e < end; ++e) {
        float4 v = xd[csr[e]];
        ax += v.x; ay += v.y; az += v.z;
    }
    float4 sf = xd[n];
    float dn = sf.w;
    float cx = dn * (ax + sf.x), cy = dn * (ay + sf.y), cz = dn * (az + sf.z);
    __half2 tmp[16];
#pragma unroll
    for (int j = 0; j < 16; ++j) {
        int f0 = 2 * j, f1 = 2 * j + 1;
        float v0 = cx * W1s[f0] + cy * W1s[F + f0] + cz * W1s[2 * F + f0] + b1s[f0];
        float v1 = cx * W1s[f1] + cy * W1s[F + f1] + cz * W1s[2 * F + f1] + b1s[f1];
        tmp[j] = __floats2half2_rn(fmaxf(v0, 0.0f), fmaxf(v1, 0.0f));
    }
    uint4* hv = (uint4*)(h1 + (size_t)n * 16);
    const uint4* tv = (const uint4*)tmp;
    hv[0] = tv[0]; hv[1] = tv[1]; hv[2] = tv[2]; hv[3] = tv[3];
}

// ================= layer 2 =================
// t[n] = dn*sum_e dinv[s]*h1[s] + dn^2*h1[n]   (W2 applied later — linearity)
__global__ void k_gather2h(const int* __restrict__ row, const int* __restrict__ csr,
                           const __half2* __restrict__ h1, const float* __restrict__ dinv,
                           __half2* __restrict__ t16) {
    int tid = threadIdx.x;
    int n = blockIdx.x * 16 + (tid >> 4);
    if (n >= NN) return;
    int j = tid & 15;
    int beg = row[n], end = row[n + 1];
    float ax = 0.0f, ay = 0.0f;
    int e = beg;
    for (; e + 3 < end; e += 4) {
        int s0 = csr[e], s1 = csr[e + 1], s2 = csr[e + 2], s3 = csr[e + 3];
        float d0 = dinv[s0], d1 = dinv[s1], d2 = dinv[s2], d3 = dinv[s3];
        float2 v0 = __half22float2(h1[s0 * 16 + j]);
        float2 v1 = __half22float2(h1[s1 * 16 + j]);
        float2 v2 = __half22float2(h1[s2 * 16 + j]);
        float2 v3 = __half22float2(h1[s3 * 16 + j]);
        ax += d0 * v0.x + d1 * v1.x + d2 * v2.x + d3 * v3.x;
        ay += d0 * v0.y + d1 * v1.y + d2 * v2.y + d3 * v3.y;
    }
    for (; e < end; ++e) {
        int s = csr[e];
        float d = dinv[s];
        float2 v = __half22float2(h1[s * 16 + j]);
        ax += d * v.x;
        ay += d * v.y;
    }
    float dn = dinv[n];
    float2 sf = __half22float2(h1[n * 16 + j]);
    float tx = dn * ax + dn * dn * sf.x;
    float ty = dn * ay + dn * dn * sf.y;
    t16[n * 16 + j] = __floats2half2_rn(tx, ty);
}

// ================= fused proj2 + relu + pool + head =================
__global__ void k_proj2_pool_head(const __half2* __restrict__ t16,
                                  const int* __restrict__ batch,
                                  const float* __restrict__ W2, const float* __restrict__ b2,
                                  const float* __restrict__ Wl, const float* __restrict__ bl,
                                  float* __restrict__ out) {
    __shared__ float W2s[F * F];
    __shared__ float ts[8][F];
    __shared__ float red[8][F];
    __shared__ float mean[F];
    __shared__ int range[2];
    int g = blockIdx.x, tid = threadIdx.x;
    for (int i = tid; i < F * F; i += 256) W2s[i] = W2[i];
    if (tid < 2) {
        int key = g + tid, lo = 0, hi = NN;
        while (lo < hi) {
            int mid = (lo + hi) >> 1;
            if (batch[mid] < key) lo = mid + 1; else hi = mid;
        }
        range[tid] = lo;
    }
    __syncthreads();
    int s = range[0], e = range[1];
    int grp = tid >> 5, f = tid & 31;
    float b2f = b2[f];
    float psum = 0.0f;
    for (int n0 = s; n0 < e; n0 += 8) {
        __syncthreads();
        if (tid < 128) {
            int nl = tid >> 4, j = tid & 15;
            int n = n0 + nl;
            if (n < e) {
                float2 v = __half22float2(t16[n * 16 + j]);
                ts[nl][2 * j]     = v.x;
                ts[nl][2 * j + 1] = v.y;
            }
        }
        __syncthreads();
        int n = n0 + grp;
        if (n < e) {
            float acc = b2f;
#pragma unroll
            for (int k = 0; k < F; k++) acc += ts[grp][k] * W2s[k * F + f];
            psum += fmaxf(acc, 0.0f);
        }
    }
    red[grp][f] = psum;
    __syncthreads();
    if (grp == 0) {
        float t = red[0][f] + red[1][f] + red[2][f] + red[3][f]
                + red[4][f] + red[5][f] + red[6][f] + red[7][f];
        mean[f] = t / fmaxf((float)(e - s), 1.0f);
    }
    __syncthreads();
    if (tid < 2) {
        float a = 0.0f;
#pragma unroll
        for (int k = 0; k < F; k++) a += mean[k] * Wl[k * 2 + tid];
        out[g * 2 + tid] = a + bl[tid];
    }
}

extern "C" void kernel_launch(void* const* d_in, const int* in_sizes, int n_in,
                              void* d_out, int out_size, void* d_ws, size_t ws_size,
                              hipStream_t stream) {
    const float* x     = (const float*)d_in[0];
    const int*   eidx  = (const int*)d_in[1];   // int32 per harness contract
    const int*   batch = (const int*)d_in[2];
    const float* W1    = (const float*)d_in[3];
    const float* b1    = (const float*)d_in[4];
    const float* W2    = (const float*)d_in[5];
    const float* b2    = (const float*)d_in[6];
    const float* Wl    = (const float*)d_in[7];
    const float* bl    = (const float*)d_in[8];
    float*       out   = (float*)d_out;

    const int* src = eidx;
    const int* dst = eidx + NE;

    // ---- workspace layout, 128B-aligned chunks ----
    char* base = (char*)d_ws;
    size_t off = 0;
    auto alloc = [&](size_t bytes) {
        void* p = base + off;
        off = (off + bytes + 127) & ~(size_t)127;
        return p;
    };
    int*     btot    = (int*)alloc(NB * sizeof(int));
    int*     bstart  = (int*)alloc((NB + 1) * sizeof(int));
    int*     cursor  = (int*)alloc(NB * sizeof(int));
    int*     row     = (int*)alloc((NN + 1) * sizeof(int));
    int*     csr     = (int*)alloc(NE * sizeof(int));
    int*     part    = (int*)alloc((size_t)NE * sizeof(int));   // packed (src<<8)|local_dst
    float*   dinv    = (float*)alloc(NN * sizeof(float));
    float4*  xd      = (float4*)alloc(NN * sizeof(float4));
    __half2* h1      = (__half2*)alloc((size_t)NN * 16 * sizeof(__half2));
    __half2* t16     = (__half2*)alloc((size_t)NN * 16 * sizeof(__half2));

    const int B = 256;
    const int gN   = (NN + B - 1) / B;            // 391
    const int gG16 = (NN + 15) / 16;              // 6250

    // ---- CSR build: bucketed counting sort (packed 4B records) ----
    hipMemsetAsync(btot, 0, NB * sizeof(int), stream);
    k_count    <<<NWGC, B,   0, stream>>>(dst, btot);
    k_bscan    <<<1,    512, 0, stream>>>(btot, bstart, cursor);
    k_partition<<<NWGP, 512, 0, stream>>>(src, dst, cursor, part);
    k_fill2    <<<NB,   B,   0, stream>>>(part, bstart, x, row, dinv, xd, csr);

    // ---- layer 1: fused 3-dim aggregate + projection (h1 fp16) ----
    k_agg1p<<<gN, B, 0, stream>>>(row, csr, xd, W1, b1, h1);

    // ---- layer 2: gather h1 (fp16 payload), W2 deferred ----
    k_gather2h<<<gG16, B, 0, stream>>>(row, csr, h1, dinv, t16);

    // ---- fused proj2 + relu + pool + head ----
    k_proj2_pool_head<<<NG, B, 0, stream>>>(t16, batch, W2, b2, Wl, bl, out);
}

// Round 9
// 188.446 us; speedup vs baseline: 1.2199x; 1.1258x over previous
//
#include <hip/hip_runtime.h>
#include <hip/hip_fp16.h>

#define NN 100000
#define NE 1600000
#define NG 512
#define F  32

#define BSH    8                              // 256 dst-nodes per bucket
#define BNODES 256
#define NB     ((NN + BNODES - 1) / BNODES)   // 391
#define CAP    5120                           // slots per bucket (mean 4092, sigma 64 -> safe)
#define PCHUNK 4096
#define NWGP   ((NE + PCHUNK - 1) / PCHUNK)   // 391 (partition)

// ---- partition edges into bucket-padded packed (src<<8)|(dst&255). WG=512 ----
// cursor[b] starts at 0; slice base = b*CAP + old_count. After kernel: cursor[b]=count.
__global__ void k_partition(const int* __restrict__ src, const int* __restrict__ dst,
                            int* __restrict__ cursor, int* __restrict__ part) {
    __shared__ int hist[NB];
    __shared__ int base[NB];
    int tid = threadIdx.x;
    for (int i = tid; i < NB; i += 512) hist[i] = 0;
    __syncthreads();
    int e0 = blockIdx.x * PCHUNK;
    int e1 = min(e0 + PCHUNK, NE);
    for (int e = e0 + tid; e < e1; e += 512) atomicAdd(&hist[dst[e] >> BSH], 1);
    __syncthreads();
    for (int i = tid; i < NB; i += 512) {
        base[i] = hist[i] ? (i * CAP + atomicAdd(&cursor[i], hist[i])) : 0;
        hist[i] = 0;
    }
    __syncthreads();
    for (int e = e0 + tid; e < e1; e += 512) {
        int d = dst[e];
        int b = d >> BSH;
        int p = base[b] + atomicAdd(&hist[b], 1);
        part[p] = (src[e] << 8) | (d & (BNODES - 1));
    }
}

// ---- fill2: per-bucket histogram+scan -> rowpack/dinv/xd; L2-local csr scatter ----
// rowpack[n] = (abs_pos << 10) | degree
__global__ void k_fill2(const int* __restrict__ part, const int* __restrict__ cursor,
                        const float* __restrict__ x,
                        int* __restrict__ rowpack, float* __restrict__ dinv,
                        float4* __restrict__ xd, int* __restrict__ csr) {
    __shared__ int cnt[BNODES];
    __shared__ int off[BNODES];
    __shared__ int lds[BNODES];
    int b = blockIdx.x, tid = threadIdx.x;
    int node0 = b << BSH;
    int s0 = b * CAP;
    int s1 = s0 + cursor[b];
    cnt[tid] = 0;
    __syncthreads();
    for (int i = s0 + tid; i < s1; i += 256) atomicAdd(&cnt[part[i] & (BNODES - 1)], 1);
    __syncthreads();
    int c = cnt[tid];
    lds[tid] = c;
    __syncthreads();
    for (int o = 1; o < 256; o <<= 1) {
        int t = (tid >= o) ? lds[tid - o] : 0;
        __syncthreads();
        lds[tid] += t;
        __syncthreads();
    }
    int excl = lds[tid] - c;
    off[tid] = excl;
    int n = node0 + tid;
    if (n < NN) {
        rowpack[n] = ((s0 + excl) << 10) | c;
        float d = rsqrtf((float)c + 1.0f);
        dinv[n] = d;
        xd[n] = make_float4(d * x[n * 3 + 0], d * x[n * 3 + 1], d * x[n * 3 + 2], d);
    }
    __syncthreads();
    for (int i = s0 + tid; i < s1; i += 256) {
        int p = part[i];
        int pos = s0 + atomicAdd(&off[p & (BNODES - 1)], 1);
        csr[pos] = p >> 8;
    }
}

// ================= layer 1: fused aggregate + project =================
// c = dinv[n]*(sum_e xd[src].xyz + xd[n].xyz); g1[n] = dinv[n]*relu(c@W1+b1) fp16
__global__ void k_agg1p(const int* __restrict__ rowpack, const int* __restrict__ csr,
                        const float4* __restrict__ xd,
                        const float* __restrict__ W1, const float* __restrict__ b1,
                        __half2* __restrict__ g1) {
    __shared__ float W1s[3 * F];
    __shared__ float b1s[F];
    int tid = threadIdx.x;
    if (tid < 3 * F) W1s[tid] = W1[tid];
    if (tid < F) b1s[tid] = b1[tid];
    __syncthreads();
    int n = blockIdx.x * blockDim.x + tid;
    if (n >= NN) return;
    int pack = rowpack[n];
    int beg = pack >> 10, end = beg + (pack & 1023);
    float ax = 0.0f, ay = 0.0f, az = 0.0f;
    int e = beg;
    for (; e + 3 < end; e += 4) {
        int s0 = csr[e], s1 = csr[e + 1], s2 = csr[e + 2], s3 = csr[e + 3];
        float4 v0 = xd[s0], v1 = xd[s1], v2 = xd[s2], v3 = xd[s3];
        ax += (v0.x + v1.x) + (v2.x + v3.x);
        ay += (v0.y + v1.y) + (v2.y + v3.y);
        az += (v0.z + v1.z) + (v2.z + v3.z);
    }
    for (; e < end; ++e) {
        float4 v = xd[csr[e]];
        ax += v.x; ay += v.y; az += v.z;
    }
    float4 sf = xd[n];
    float dn = sf.w;
    float cx = dn * (ax + sf.x), cy = dn * (ay + sf.y), cz = dn * (az + sf.z);
    __half2 tmp[16];
#pragma unroll
    for (int j = 0; j < 16; ++j) {
        int f0 = 2 * j, f1 = 2 * j + 1;
        float v0 = cx * W1s[f0] + cy * W1s[F + f0] + cz * W1s[2 * F + f0] + b1s[f0];
        float v1 = cx * W1s[f1] + cy * W1s[F + f1] + cz * W1s[2 * F + f1] + b1s[f1];
        tmp[j] = __floats2half2_rn(dn * fmaxf(v0, 0.0f), dn * fmaxf(v1, 0.0f));
    }
    uint4* hv = (uint4*)(g1 + (size_t)n * 16);
    const uint4* tv = (const uint4*)tmp;
    hv[0] = tv[0]; hv[1] = tv[1]; hv[2] = tv[2]; hv[3] = tv[3];
}

// ================= layer 2 =================
// t[n] = dinv[n]*(sum_e g1[s] + g1[n])     (dinv[s] pre-folded into g1; W2 deferred)
__global__ void k_gather2h(const int* __restrict__ rowpack, const int* __restrict__ csr,
                           const __half2* __restrict__ g1, const float* __restrict__ dinv,
                           __half2* __restrict__ t16) {
    int tid = threadIdx.x;
    int n = blockIdx.x * 16 + (tid >> 4);
    if (n >= NN) return;
    int j = tid & 15;
    int pack = rowpack[n];
    int beg = pack >> 10, end = beg + (pack & 1023);
    float ax = 0.0f, ay = 0.0f;
    int e = beg;
    for (; e + 3 < end; e += 4) {
        int s0 = csr[e], s1 = csr[e + 1], s2 = csr[e + 2], s3 = csr[e + 3];
        float2 v0 = __half22float2(g1[s0 * 16 + j]);
        float2 v1 = __half22float2(g1[s1 * 16 + j]);
        float2 v2 = __half22float2(g1[s2 * 16 + j]);
        float2 v3 = __half22float2(g1[s3 * 16 + j]);
        ax += (v0.x + v1.x) + (v2.x + v3.x);
        ay += (v0.y + v1.y) + (v2.y + v3.y);
    }
    for (; e < end; ++e) {
        float2 v = __half22float2(g1[csr[e] * 16 + j]);
        ax += v.x;
        ay += v.y;
    }
    float dn = dinv[n];
    float2 sf = __half22float2(g1[n * 16 + j]);
    t16[n * 16 + j] = __floats2half2_rn(dn * (ax + sf.x), dn * (ay + sf.y));
}

// ================= fused proj2 + relu + pool + head =================
__global__ void k_proj2_pool_head(const __half2* __restrict__ t16,
                                  const int* __restrict__ batch,
                                  const float* __restrict__ W2, const float* __restrict__ b2,
                                  const float* __restrict__ Wl, const float* __restrict__ bl,
                                  float* __restrict__ out) {
    __shared__ float W2s[F * F];
    __shared__ float ts[8][F];
    __shared__ float red[8][F];
    __shared__ float mean[F];
    __shared__ int range[2];
    int g = blockIdx.x, tid = threadIdx.x;
    for (int i = tid; i < F * F; i += 256) W2s[i] = W2[i];
    if (tid < 2) {
        int key = g + tid, lo = 0, hi = NN;
        while (lo < hi) {
            int mid = (lo + hi) >> 1;
            if (batch[mid] < key) lo = mid + 1; else hi = mid;
        }
        range[tid] = lo;
    }
    __syncthreads();
    int s = range[0], e = range[1];
    int grp = tid >> 5, f = tid & 31;
    float b2f = b2[f];
    float psum = 0.0f;
    for (int n0 = s; n0 < e; n0 += 8) {
        __syncthreads();
        if (tid < 128) {
            int nl = tid >> 4, j = tid & 15;
            int n = n0 + nl;
            if (n < e) {
                float2 v = __half22float2(t16[n * 16 + j]);
                ts[nl][2 * j]     = v.x;
                ts[nl][2 * j + 1] = v.y;
            }
        }
        __syncthreads();
        int n = n0 + grp;
        if (n < e) {
            float acc = b2f;
#pragma unroll
            for (int k = 0; k < F; k++) acc += ts[grp][k] * W2s[k * F + f];
            psum += fmaxf(acc, 0.0f);
        }
    }
    red[grp][f] = psum;
    __syncthreads();
    if (grp == 0) {
        float t = red[0][f] + red[1][f] + red[2][f] + red[3][f]
                + red[4][f] + red[5][f] + red[6][f] + red[7][f];
        mean[f] = t / fmaxf((float)(e - s), 1.0f);
    }
    __syncthreads();
    if (tid < 2) {
        float a = 0.0f;
#pragma unroll
        for (int k = 0; k < F; k++) a += mean[k] * Wl[k * 2 + tid];
        out[g * 2 + tid] = a + bl[tid];
    }
}

extern "C" void kernel_launch(void* const* d_in, const int* in_sizes, int n_in,
                              void* d_out, int out_size, void* d_ws, size_t ws_size,
                              hipStream_t stream) {
    const float* x     = (const float*)d_in[0];
    const int*   eidx  = (const int*)d_in[1];   // int32 per harness contract
    const int*   batch = (const int*)d_in[2];
    const float* W1    = (const float*)d_in[3];
    const float* b1    = (const float*)d_in[4];
    const float* W2    = (const float*)d_in[5];
    const float* b2    = (const float*)d_in[6];
    const float* Wl    = (const float*)d_in[7];
    const float* bl    = (const float*)d_in[8];
    float*       out   = (float*)d_out;

    const int* src = eidx;
    const int* dst = eidx + NE;

    // ---- workspace layout, 128B-aligned chunks ----
    char* base = (char*)d_ws;
    size_t off = 0;
    auto alloc = [&](size_t bytes) {
        void* p = base + off;
        off = (off + bytes + 127) & ~(size_t)127;
        return p;
    };
    int*     cursor  = (int*)alloc(NB * sizeof(int));
    int*     rowpack = (int*)alloc(NN * sizeof(int));
    int*     part    = (int*)alloc((size_t)NB * CAP * sizeof(int));  // bucket-padded
    int*     csr     = (int*)alloc((size_t)NB * CAP * sizeof(int));  // bucket-padded
    float*   dinv    = (float*)alloc(NN * sizeof(float));
    float4*  xd      = (float4*)alloc(NN * sizeof(float4));
    __half2* g1      = (__half2*)alloc((size_t)NN * 16 * sizeof(__half2));
    __half2* t16     = (__half2*)alloc((size_t)NN * 16 * sizeof(__half2));

    const int B = 256;
    const int gN   = (NN + B - 1) / B;            // 391
    const int gG16 = (NN + 15) / 16;              // 6250

    // ---- CSR build: single-scan bucketed counting sort (fixed-capacity buckets) ----
    hipMemsetAsync(cursor, 0, NB * sizeof(int), stream);
    k_partition<<<NWGP, 512, 0, stream>>>(src, dst, cursor, part);
    k_fill2    <<<NB,   B,   0, stream>>>(part, cursor, x, rowpack, dinv, xd, csr);

    // ---- layer 1: fused 3-dim aggregate + projection (g1 = dinv*h1, fp16) ----
    k_agg1p<<<gN, B, 0, stream>>>(rowpack, csr, xd, W1, b1, g1);

    // ---- layer 2: gather g1 (fp16, dinv pre-folded), W2 deferred ----
    k_gather2h<<<gG16, B, 0, stream>>>(rowpack, csr, g1, dinv, t16);

    // ---- fused proj2 + relu + pool + head ----
    k_proj2_pool_head<<<NG, B, 0, stream>>>(t16, batch, W2, b2, Wl, bl, out);
}

// Round 10
// 177.328 us; speedup vs baseline: 1.2963x; 1.0627x over previous
//
#include <hip/hip_runtime.h>
#include <hip/hip_fp16.h>

#define NN 100000
#define NE 1600000
#define NG 512
#define F  32

#define BSH    8                              // 256 dst-nodes per bucket
#define BNODES 256
#define NB     ((NN + BNODES - 1) / BNODES)   // 391
#define CAP    5120                           // slots/bucket (mean 4092, sigma 64 -> safe)
#define PCHUNK 4096
#define NWGP   ((NE + PCHUNK - 1) / PCHUNK)   // 391

// ---- partition edges into bucket-padded packed (src<<8)|(dst&255). WG=512 ----
__global__ void k_partition(const int* __restrict__ src, const int* __restrict__ dst,
                            int* __restrict__ cursor, int* __restrict__ part) {
    __shared__ int hist[NB];
    __shared__ int base[NB];
    int tid = threadIdx.x;
    for (int i = tid; i < NB; i += 512) hist[i] = 0;
    __syncthreads();
    int e0 = blockIdx.x * PCHUNK;
    int e1 = min(e0 + PCHUNK, NE);
    for (int e = e0 + tid; e < e1; e += 512) atomicAdd(&hist[dst[e] >> BSH], 1);
    __syncthreads();
    for (int i = tid; i < NB; i += 512) {
        base[i] = hist[i] ? (i * CAP + atomicAdd(&cursor[i], hist[i])) : 0;
        hist[i] = 0;
    }
    __syncthreads();
    for (int e = e0 + tid; e < e1; e += 512) {
        int d = dst[e];
        int b = d >> BSH;
        int p = base[b] + atomicAdd(&hist[b], 1);
        part[p] = (src[e] << 8) | (d & (BNODES - 1));
    }
}

// ---- fill2a: per-bucket histogram+scan -> rowpack[(pos<<10)|deg], dinv, xd ----
__global__ void k_fill2a(const int* __restrict__ part, const int* __restrict__ cursor,
                         const float* __restrict__ x,
                         int* __restrict__ rowpack, float* __restrict__ dinv,
                         float4* __restrict__ xd) {
    __shared__ int cnt[BNODES];
    __shared__ int lds[BNODES];
    int b = blockIdx.x, tid = threadIdx.x;
    int node0 = b << BSH;
    int s0 = b * CAP, s1 = s0 + cursor[b];
    cnt[tid] = 0;
    __syncthreads();
    for (int i = s0 + tid; i < s1; i += 256) atomicAdd(&cnt[part[i] & (BNODES - 1)], 1);
    __syncthreads();
    int c = cnt[tid];
    lds[tid] = c;
    __syncthreads();
    for (int o = 1; o < 256; o <<= 1) {
        int t = (tid >= o) ? lds[tid - o] : 0;
        __syncthreads();
        lds[tid] += t;
        __syncthreads();
    }
    int excl = lds[tid] - c;
    int n = node0 + tid;
    if (n < NN) {
        rowpack[n] = ((s0 + excl) << 10) | c;
        float d = rsqrtf((float)c + 1.0f);
        dinv[n] = d;
        xd[n] = make_float4(d * x[n * 3 + 0], d * x[n * 3 + 1], d * x[n * 3 + 2], d);
    }
}

// ---- fill2b: LDS-staged csr scatter + coalesced write-out + fused layer 1 ----
// g1[n] = dinv[n] * relu( (dinv[n]*(sum_e xd[s]+xd[n])) @ W1 + b1 )  fp16
__global__ void k_fill2b(const int* __restrict__ part, const int* __restrict__ cursor,
                         const int* __restrict__ rowpack, const float4* __restrict__ xd,
                         const float* __restrict__ W1, const float* __restrict__ b1,
                         int* __restrict__ csr, __half2* __restrict__ g1) {
    __shared__ int lcsr[CAP];
    __shared__ int off[BNODES];
    __shared__ float W1s[3 * F];
    __shared__ float b1s[F];
    int b = blockIdx.x, tid = threadIdx.x;
    int node0 = b << BSH;
    int s0 = b * CAP;
    int cnt = cursor[b];
    if (tid < 3 * F) W1s[tid] = W1[tid];
    if (tid < F) b1s[tid] = b1[tid];
    int n = node0 + tid;
    int pack = (n < NN) ? rowpack[n] : (s0 << 10);
    off[tid] = (pack >> 10) - s0;
    __syncthreads();
    for (int i = tid; i < cnt; i += 256) {
        int p = part[s0 + i];
        int pos = atomicAdd(&off[p & (BNODES - 1)], 1);
        lcsr[pos] = p >> 8;
    }
    __syncthreads();
    for (int i = tid; i < cnt; i += 256) csr[s0 + i] = lcsr[i];   // coalesced
    if (n < NN) {
        int deg = pack & 1023;
        int beg = (pack >> 10) - s0;
        int end = beg + deg;
        float ax = 0.0f, ay = 0.0f, az = 0.0f;
        int e = beg;
        for (; e + 3 < end; e += 4) {
            int i0 = lcsr[e], i1 = lcsr[e + 1], i2 = lcsr[e + 2], i3 = lcsr[e + 3];
            float4 v0 = xd[i0], v1 = xd[i1], v2 = xd[i2], v3 = xd[i3];
            ax += (v0.x + v1.x) + (v2.x + v3.x);
            ay += (v0.y + v1.y) + (v2.y + v3.y);
            az += (v0.z + v1.z) + (v2.z + v3.z);
        }
        for (; e < end; ++e) {
            float4 v = xd[lcsr[e]];
            ax += v.x; ay += v.y; az += v.z;
        }
        float4 sf = xd[n];
        float dn = sf.w;
        float cx = dn * (ax + sf.x), cy = dn * (ay + sf.y), cz = dn * (az + sf.z);
        __half2 tmp[16];
#pragma unroll
        for (int j = 0; j < 16; ++j) {
            int f0 = 2 * j, f1 = 2 * j + 1;
            float v0 = cx * W1s[f0] + cy * W1s[F + f0] + cz * W1s[2 * F + f0] + b1s[f0];
            float v1 = cx * W1s[f1] + cy * W1s[F + f1] + cz * W1s[2 * F + f1] + b1s[f1];
            tmp[j] = __floats2half2_rn(dn * fmaxf(v0, 0.0f), dn * fmaxf(v1, 0.0f));
        }
        uint4* hv = (uint4*)(g1 + (size_t)n * 16);
        const uint4* tv = (const uint4*)tmp;
        hv[0] = tv[0]; hv[1] = tv[1]; hv[2] = tv[2]; hv[3] = tv[3];
    }
}

// ---- gather2p: gather g1 + fp32 t + proj2(W2)+relu + per-block pool -> gsum ----
__global__ void k_gather2p(const int* __restrict__ rowpack, const int* __restrict__ csr,
                           const __half2* __restrict__ g1, const float* __restrict__ dinv,
                           const int* __restrict__ batch,
                           const float* __restrict__ W2, const float* __restrict__ b2,
                           float* __restrict__ gsum) {
    __shared__ float W2s[F * F];
    __shared__ float b2s[F];
    __shared__ float ts[16][F];
    __shared__ float hs[16][F];
    __shared__ int bat[16];
    int tid = threadIdx.x;
    int nb = blockIdx.x * 16;
    for (int i = tid; i < F * F; i += 256) W2s[i] = W2[i];
    if (tid < F) b2s[tid] = b2[tid];
    if (tid < 16) bat[tid] = batch[nb + tid];
    int nl = tid >> 4, j = tid & 15;
    int n = nb + nl;
    {
        int pack = rowpack[n];
        int beg = pack >> 10, end = beg + (pack & 1023);
        float ax = 0.0f, ay = 0.0f;
        int e = beg;
        for (; e + 3 < end; e += 4) {
            int s0 = csr[e], s1 = csr[e + 1], s2 = csr[e + 2], s3 = csr[e + 3];
            float2 v0 = __half22float2(g1[s0 * 16 + j]);
            float2 v1 = __half22float2(g1[s1 * 16 + j]);
            float2 v2 = __half22float2(g1[s2 * 16 + j]);
            float2 v3 = __half22float2(g1[s3 * 16 + j]);
            ax += (v0.x + v1.x) + (v2.x + v3.x);
            ay += (v0.y + v1.y) + (v2.y + v3.y);
        }
        for (; e < end; ++e) {
            float2 v = __half22float2(g1[csr[e] * 16 + j]);
            ax += v.x; ay += v.y;
        }
        float dn = dinv[n];
        float2 sf = __half22float2(g1[n * 16 + j]);
        ts[nl][2 * j]     = dn * (ax + sf.x);
        ts[nl][2 * j + 1] = dn * (ay + sf.y);
    }
    __syncthreads();
    {
        int f = tid & 31;
        int nn0 = tid >> 5;           // 0..7
#pragma unroll
        for (int pass = 0; pass < 2; ++pass) {
            int nn = nn0 + pass * 8;
            float acc = b2s[f];
#pragma unroll
            for (int k = 0; k < F; ++k) acc += ts[nn][k] * W2s[k * F + f];
            hs[nn][f] = fmaxf(acc, 0.0f);
        }
    }
    __syncthreads();
    if (tid < F) {
        int g0 = bat[0], gmax = bat[15];
        for (int g = g0; g <= gmax; ++g) {
            float s = 0.0f;
#pragma unroll
            for (int i = 0; i < 16; ++i) if (bat[i] == g) s += hs[i][tid];
            atomicAdd(&gsum[g * F + tid], s);
        }
    }
}

// ---- head: out[g] = (gsum[g]/max(cnt,1)) @ Wl + bl ----
__global__ void k_head(const float* __restrict__ gsum, const int* __restrict__ batch,
                       const float* __restrict__ Wl, const float* __restrict__ bl,
                       float* __restrict__ out) {
    int g = blockIdx.x * blockDim.x + threadIdx.x;
    if (g >= NG) return;
    int lo = 0, hi = NN;
    while (lo < hi) { int m = (lo + hi) >> 1; if (batch[m] < g) lo = m + 1; else hi = m; }
    int s = lo;
    lo = 0; hi = NN;
    while (lo < hi) { int m = (lo + hi) >> 1; if (batch[m] < g + 1) lo = m + 1; else hi = m; }
    float inv = 1.0f / fmaxf((float)(lo - s), 1.0f);
    float a0 = 0.0f, a1 = 0.0f;
#pragma unroll
    for (int k = 0; k < F; ++k) {
        float m = gsum[g * F + k] * inv;
        a0 += m * Wl[k * 2 + 0];
        a1 += m * Wl[k * 2 + 1];
    }
    out[g * 2 + 0] = a0 + bl[0];
    out[g * 2 + 1] = a1 + bl[1];
}

extern "C" void kernel_launch(void* const* d_in, const int* in_sizes, int n_in,
                              void* d_out, int out_size, void* d_ws, size_t ws_size,
                              hipStream_t stream) {
    const float* x     = (const float*)d_in[0];
    const int*   eidx  = (const int*)d_in[1];   // int32 per harness contract
    const int*   batch = (const int*)d_in[2];
    const float* W1    = (const float*)d_in[3];
    const float* b1    = (const float*)d_in[4];
    const float* W2    = (const float*)d_in[5];
    const float* b2    = (const float*)d_in[6];
    const float* Wl    = (const float*)d_in[7];
    const float* bl    = (const float*)d_in[8];
    float*       out   = (float*)d_out;

    const int* src = eidx;
    const int* dst = eidx + NE;

    // ---- workspace layout, 128B-aligned chunks ----
    char* base = (char*)d_ws;
    size_t off = 0;
    auto alloc = [&](size_t bytes) {
        void* p = base + off;
        off = (off + bytes + 127) & ~(size_t)127;
        return p;
    };
    int*     cursor  = (int*)alloc(NB * sizeof(int));
    int*     rowpack = (int*)alloc(NN * sizeof(int));
    int*     part    = (int*)alloc((size_t)NB * CAP * sizeof(int));
    int*     csr     = (int*)alloc((size_t)NB * CAP * sizeof(int));
    float*   dinv    = (float*)alloc(NN * sizeof(float));
    float4*  xd      = (float4*)alloc(NN * sizeof(float4));
    __half2* g1      = (__half2*)alloc((size_t)NN * 16 * sizeof(__half2));
    float*   gsum    = (float*)alloc((size_t)NG * F * sizeof(float));

    const int B = 256;
    const int gG16 = NN / 16;   // 6250, exact

    hipMemsetAsync(cursor, 0, NB * sizeof(int), stream);
    hipMemsetAsync(gsum, 0, (size_t)NG * F * sizeof(float), stream);

    // ---- CSR build ----
    k_partition<<<NWGP, 512, 0, stream>>>(src, dst, cursor, part);
    k_fill2a   <<<NB,   B,   0, stream>>>(part, cursor, x, rowpack, dinv, xd);
    k_fill2b   <<<NB,   B,   0, stream>>>(part, cursor, rowpack, xd, W1, b1, csr, g1);

    // ---- layer 2 gather + proj2 + relu + pool (fused) ----
    k_gather2p<<<gG16, B, 0, stream>>>(rowpack, csr, g1, dinv, batch, W2, b2, gsum);

    // ---- head ----
    k_head<<<(NG + B - 1) / B, B, 0, stream>>>(gsum, batch, Wl, bl, out);
}

// Round 11
// 170.862 us; speedup vs baseline: 1.3454x; 1.0378x over previous
//
#include <hip/hip_runtime.h>
#include <hip/hip_fp16.h>

#define NN 100000
#define NE 1600000
#define NG 512
#define F  32

#define BSH    8                              // 256 dst-nodes per bucket
#define BNODES 256
#define NB     ((NN + BNODES - 1) / BNODES)   // 391
#define CAP    5120                           // slots/bucket (mean 4092, sigma 64 -> safe)
#define PCHUNK 4096
#define EPT    8                              // edges per thread (PCHUNK/512)
#define NWGP   ((NE + PCHUNK - 1) / PCHUNK)   // 391

// ---- partition: in-LDS counting sort per chunk -> coalesced bucket-run writes ----
__global__ void k_partition(const int* __restrict__ src, const int* __restrict__ dst,
                            int* __restrict__ cursor, int* __restrict__ part) {
    __shared__ int   s_cnt[NB];      // hist, then reused as rank counter
    __shared__ int   s_scan[512];
    __shared__ int   s_lstart[NB];
    __shared__ int   s_base[NB];
    __shared__ int   lsort[PCHUNK];
    __shared__ short lbkt[PCHUNK];
    int tid = threadIdx.x;
    for (int i = tid; i < NB; i += 512) s_cnt[i] = 0;
    __syncthreads();
    int e0 = blockIdx.x * PCHUNK;
    int e1 = min(e0 + PCHUNK, NE);
    int pk[EPT]; short bk[EPT];
    int m = 0;
#pragma unroll
    for (int k = 0; k < EPT; ++k) {
        int e = e0 + tid + k * 512;
        if (e < e1) {
            int d = dst[e];
            pk[m] = (src[e] << 8) | (d & (BNODES - 1));
            bk[m] = (short)(d >> BSH);
            atomicAdd(&s_cnt[bk[m]], 1);
            ++m;
        }
    }
    __syncthreads();
    int cv = (tid < NB) ? s_cnt[tid] : 0;
    s_scan[tid] = cv;
    __syncthreads();
    for (int o = 1; o < 512; o <<= 1) {
        int t = (tid >= o) ? s_scan[tid - o] : 0;
        __syncthreads();
        s_scan[tid] += t;
        __syncthreads();
    }
    if (tid < NB) {
        s_lstart[tid] = s_scan[tid] - cv;
        if (cv) s_base[tid] = tid * CAP + atomicAdd(&cursor[tid], cv);
        s_cnt[tid] = 0;   // reuse as rank counter
    }
    __syncthreads();
    for (int k = 0; k < m; ++k) {
        int b = bk[k];
        int r = s_lstart[b] + atomicAdd(&s_cnt[b], 1);
        lsort[r] = pk[k];
        lbkt[r]  = (short)b;
    }
    __syncthreads();
    int cnt = e1 - e0;
    for (int i = tid; i < cnt; i += 512) {
        int b = lbkt[i];
        part[s_base[b] + (i - s_lstart[b])] = lsort[i];   // coalesced per-bucket runs
    }
}

// ---- fill2a: per-bucket histogram+scan -> rowpack[(pos<<10)|deg], dinv, xd ----
__global__ void k_fill2a(const int* __restrict__ part, const int* __restrict__ cursor,
                         const float* __restrict__ x,
                         int* __restrict__ rowpack, float* __restrict__ dinv,
                         float4* __restrict__ xd) {
    __shared__ int cnt[BNODES];
    __shared__ int lds[BNODES];
    int b = blockIdx.x, tid = threadIdx.x;
    int node0 = b << BSH;
    int s0 = b * CAP, s1 = s0 + cursor[b];
    cnt[tid] = 0;
    __syncthreads();
    for (int i = s0 + tid; i < s1; i += 256) atomicAdd(&cnt[part[i] & (BNODES - 1)], 1);
    __syncthreads();
    int c = cnt[tid];
    lds[tid] = c;
    __syncthreads();
    for (int o = 1; o < 256; o <<= 1) {
        int t = (tid >= o) ? lds[tid - o] : 0;
        __syncthreads();
        lds[tid] += t;
        __syncthreads();
    }
    int excl = lds[tid] - c;
    int n = node0 + tid;
    if (n < NN) {
        rowpack[n] = ((s0 + excl) << 10) | c;
        float d = rsqrtf((float)c + 1.0f);
        dinv[n] = d;
        xd[n] = make_float4(d * x[n * 3 + 0], d * x[n * 3 + 1], d * x[n * 3 + 2], d);
    }
}

// ---- fill2b: LDS-staged csr scatter + coalesced write-out + fused layer 1 ----
// g1[n] = dinv[n] * relu( (dinv[n]*(sum_e xd[s]+xd[n])) @ W1 + b1 )  fp16
__global__ void k_fill2b(const int* __restrict__ part, const int* __restrict__ cursor,
                         const int* __restrict__ rowpack, const float4* __restrict__ xd,
                         const float* __restrict__ W1, const float* __restrict__ b1,
                         int* __restrict__ csr, __half2* __restrict__ g1) {
    __shared__ int lcsr[CAP];
    __shared__ int off[BNODES];
    __shared__ float W1s[3 * F];
    __shared__ float b1s[F];
    int b = blockIdx.x, tid = threadIdx.x;
    int node0 = b << BSH;
    int s0 = b * CAP;
    int cnt = cursor[b];
    if (tid < 3 * F) W1s[tid] = W1[tid];
    if (tid < F) b1s[tid] = b1[tid];
    int n = node0 + tid;
    int pack = (n < NN) ? rowpack[n] : (s0 << 10);
    off[tid] = (pack >> 10) - s0;
    __syncthreads();
    for (int i = tid; i < cnt; i += 256) {
        int p = part[s0 + i];
        int pos = atomicAdd(&off[p & (BNODES - 1)], 1);
        lcsr[pos] = p >> 8;
    }
    __syncthreads();
    for (int i = tid; i < cnt; i += 256) csr[s0 + i] = lcsr[i];   // coalesced
    if (n < NN) {
        int deg = pack & 1023;
        int beg = (pack >> 10) - s0;
        int end = beg + deg;
        float ax = 0.0f, ay = 0.0f, az = 0.0f;
        int e = beg;
        for (; e + 3 < end; e += 4) {
            int i0 = lcsr[e], i1 = lcsr[e + 1], i2 = lcsr[e + 2], i3 = lcsr[e + 3];
            float4 v0 = xd[i0], v1 = xd[i1], v2 = xd[i2], v3 = xd[i3];
            ax += (v0.x + v1.x) + (v2.x + v3.x);
            ay += (v0.y + v1.y) + (v2.y + v3.y);
            az += (v0.z + v1.z) + (v2.z + v3.z);
        }
        for (; e < end; ++e) {
            float4 v = xd[lcsr[e]];
            ax += v.x; ay += v.y; az += v.z;
        }
        float4 sf = xd[n];
        float dn = sf.w;
        float cx = dn * (ax + sf.x), cy = dn * (ay + sf.y), cz = dn * (az + sf.z);
        __half2 tmp[16];
#pragma unroll
        for (int j = 0; j < 16; ++j) {
            int f0 = 2 * j, f1 = 2 * j + 1;
            float v0 = cx * W1s[f0] + cy * W1s[F + f0] + cz * W1s[2 * F + f0] + b1s[f0];
            float v1 = cx * W1s[f1] + cy * W1s[F + f1] + cz * W1s[2 * F + f1] + b1s[f1];
            tmp[j] = __floats2half2_rn(dn * fmaxf(v0, 0.0f), dn * fmaxf(v1, 0.0f));
        }
        uint4* hv = (uint4*)(g1 + (size_t)n * 16);
        const uint4* tv = (const uint4*)tmp;
        hv[0] = tv[0]; hv[1] = tv[1]; hv[2] = tv[2]; hv[3] = tv[3];
    }
}

// ---- gather2p: gather g1 + fp32 t + proj2(W2)+relu + per-block pool -> gsum ----
__global__ void k_gather2p(const int* __restrict__ rowpack, const int* __restrict__ csr,
                           const __half2* __restrict__ g1, const float* __restrict__ dinv,
                           const int* __restrict__ batch,
                           const float* __restrict__ W2, const float* __restrict__ b2,
                           float* __restrict__ gsum) {
    __shared__ float W2s[F * F];
    __shared__ float b2s[F];
    __shared__ float ts[16][F];
    __shared__ float hs[16][F];
    __shared__ int bat[16];
    int tid = threadIdx.x;
    int nb = blockIdx.x * 16;
    for (int i = tid; i < F * F; i += 256) W2s[i] = W2[i];
    if (tid < F) b2s[tid] = b2[tid];
    if (tid < 16) bat[tid] = batch[nb + tid];
    int nl = tid >> 4, j = tid & 15;
    int n = nb + nl;
    {
        int pack = rowpack[n];
        int beg = pack >> 10, end = beg + (pack & 1023);
        float ax = 0.0f, ay = 0.0f;
        int e = beg;
        for (; e + 3 < end; e += 4) {
            int s0 = csr[e], s1 = csr[e + 1], s2 = csr[e + 2], s3 = csr[e + 3];
            float2 v0 = __half22float2(g1[s0 * 16 + j]);
            float2 v1 = __half22float2(g1[s1 * 16 + j]);
            float2 v2 = __half22float2(g1[s2 * 16 + j]);
            float2 v3 = __half22float2(g1[s3 * 16 + j]);
            ax += (v0.x + v1.x) + (v2.x + v3.x);
            ay += (v0.y + v1.y) + (v2.y + v3.y);
        }
        for (; e < end; ++e) {
            float2 v = __half22float2(g1[csr[e] * 16 + j]);
            ax += v.x; ay += v.y;
        }
        float dn = dinv[n];
        float2 sf = __half22float2(g1[n * 16 + j]);
        ts[nl][2 * j]     = dn * (ax + sf.x);
        ts[nl][2 * j + 1] = dn * (ay + sf.y);
    }
    __syncthreads();
    {
        int f = tid & 31;
        int nn0 = tid >> 5;           // 0..7
#pragma unroll
        for (int pass = 0; pass < 2; ++pass) {
            int nn = nn0 + pass * 8;
            float acc = b2s[f];
#pragma unroll
            for (int k = 0; k < F; ++k) acc += ts[nn][k] * W2s[k * F + f];
            hs[nn][f] = fmaxf(acc, 0.0f);
        }
    }
    __syncthreads();
    if (tid < F) {
        int g0 = bat[0], gmax = bat[15];
        for (int g = g0; g <= gmax; ++g) {
            float s = 0.0f;
#pragma unroll
            for (int i = 0; i < 16; ++i) if (bat[i] == g) s += hs[i][tid];
            atomicAdd(&gsum[g * F + tid], s);
        }
    }
}

// ---- head: out[g] = (gsum[g]/max(cnt,1)) @ Wl + bl ----
__global__ void k_head(const float* __restrict__ gsum, const int* __restrict__ batch,
                       const float* __restrict__ Wl, const float* __restrict__ bl,
                       float* __restrict__ out) {
    int g = blockIdx.x * blockDim.x + threadIdx.x;
    if (g >= NG) return;
    int lo = 0, hi = NN;
    while (lo < hi) { int m = (lo + hi) >> 1; if (batch[m] < g) lo = m + 1; else hi = m; }
    int s = lo;
    lo = 0; hi = NN;
    while (lo < hi) { int m = (lo + hi) >> 1; if (batch[m] < g + 1) lo = m + 1; else hi = m; }
    float inv = 1.0f / fmaxf((float)(lo - s), 1.0f);
    float a0 = 0.0f, a1 = 0.0f;
#pragma unroll
    for (int k = 0; k < F; ++k) {
        float m = gsum[g * F + k] * inv;
        a0 += m * Wl[k * 2 + 0];
        a1 += m * Wl[k * 2 + 1];
    }
    out[g * 2 + 0] = a0 + bl[0];
    out[g * 2 + 1] = a1 + bl[1];
}

extern "C" void kernel_launch(void* const* d_in, const int* in_sizes, int n_in,
                              void* d_out, int out_size, void* d_ws, size_t ws_size,
                              hipStream_t stream) {
    const float* x     = (const float*)d_in[0];
    const int*   eidx  = (const int*)d_in[1];   // int32 per harness contract
    const int*   batch = (const int*)d_in[2];
    const float* W1    = (const float*)d_in[3];
    const float* b1    = (const float*)d_in[4];
    const float* W2    = (const float*)d_in[5];
    const float* b2    = (const float*)d_in[6];
    const float* Wl    = (const float*)d_in[7];
    const float* bl    = (const float*)d_in[8];
    float*       out   = (float*)d_out;

    const int* src = eidx;
    const int* dst = eidx + NE;

    // ---- workspace layout, 128B-aligned chunks ----
    char* base = (char*)d_ws;
    size_t off = 0;
    auto alloc = [&](size_t bytes) {
        void* p = base + off;
        off = (off + bytes + 127) & ~(size_t)127;
        return p;
    };
    // cursor + gsum contiguous -> single memset
    int*     cursor  = (int*)alloc(NB * sizeof(int) + (size_t)NG * F * sizeof(float));
    float*   gsum    = (float*)(cursor + NB);
    int*     rowpack = (int*)alloc(NN * sizeof(int));
    int*     part    = (int*)alloc((size_t)NB * CAP * sizeof(int));
    int*     csr     = (int*)alloc((size_t)NB * CAP * sizeof(int));
    float*   dinv    = (float*)alloc(NN * sizeof(float));
    float4*  xd      = (float4*)alloc(NN * sizeof(float4));
    __half2* g1      = (__half2*)alloc((size_t)NN * 16 * sizeof(__half2));

    const int B = 256;
    const int gG16 = NN / 16;   // 6250, exact

    hipMemsetAsync(cursor, 0, NB * sizeof(int) + (size_t)NG * F * sizeof(float), stream);

    // ---- CSR build ----
    k_partition<<<NWGP, 512, 0, stream>>>(src, dst, cursor, part);
    k_fill2a   <<<NB,   B,   0, stream>>>(part, cursor, x, rowpack, dinv, xd);
    k_fill2b   <<<NB,   B,   0, stream>>>(part, cursor, rowpack, xd, W1, b1, csr, g1);

    // ---- layer 2 gather + proj2 + relu + pool (fused) ----
    k_gather2p<<<gG16, B, 0, stream>>>(rowpack, csr, g1, dinv, batch, W2, b2, gsum);

    // ---- head ----
    k_head<<<(NG + B - 1) / B, B, 0, stream>>>(gsum, batch, Wl, bl, out);
}